// Round 13
// baseline (168.964 us; speedup 1.0000x reference)
//
#include <hip/hip_runtime.h>

#define NR 131072
#define DD 32
#define KK 64
#define BETA_C 10.0f
#define NB1 (NR / 256)  // 512 phase1/scatter blocks
#define WROWS 256       // rows per syrk worker
#define GRIDW 640       // >= sum ceil(c_k/WROWS) <= 512+64 = 576
#define PSTR 576        // per-worker partial stride (floats)
#define TRI(i, j) ((i) * ((i) + 1) / 2 + (j))

// ---------------------------------------------------------------------------
// ws layout (float-indexed), ws_size = 256 MiB. NO memset: every slot read by
// a later kernel is unconditionally written by an earlier one (verified
// slot-cover in syrk flush; planner writes all of wk/cursor/woffK/nwK).
//   [0,64)        hist_g (int)     [64,128)  woffK (int)   [128,192) nwK (int)
//   [192,256)     cursor (int)     [256,416) wk (uchar GRIDW)
//   [416,1056)    wbase (int)      [1056,1696) wcnt (int)
//   [1696,1760)   lossPart (float 64)
//   [2048,34816)  fillPart  (float [NB1][64], coalesced per block)
//   [34816,67584) histPart  (int   [NB1][64])
//   [67584,100352) pred8 (uchar N)
//   [100352,468992) m2part (float [GRIDW][PSTR]; 528 tri + 32 sums used)
//   [468992,...)  xsort (N*D floats)
// ---------------------------------------------------------------------------

// phase 1 (R8-verbatim core): one row/thread, centers via wave-uniform s_load
// path, 63-shuffle transpose-reduce. Flush = plain coalesced per-block
// partial stores (no global atomics, nothing pre-zeroed).
__global__ __launch_bounds__(256) void phase1_kernel(
    const float* __restrict__ x, const float* __restrict__ centers,
    float* __restrict__ fillPart, int* __restrict__ histPart,
    unsigned char* __restrict__ pred_g) {
  __shared__ float cnS[KK];
  __shared__ float fillW[4][KK];
  __shared__ int histS[KK];

  const int tid = threadIdx.x;
  const int lane = tid & 63;
  const int wid = tid >> 6;
  const int b = blockIdx.x;

  if (tid < KK) {
    float s = 0.f;
    const float* cp = centers + tid * DD;
#pragma unroll
    for (int j = 0; j < DD; ++j) s += cp[j] * cp[j];
    cnS[tid] = s;
    histS[tid] = 0;
  }
  __syncthreads();

  const int row = b * 256 + tid;  // grid == NR/256 exactly

  float xr[DD];
  const float4* xp = (const float4*)(x + (size_t)row * DD);
#pragma unroll
  for (int j = 0; j < 8; ++j) {
    const float4 v = xp[j];
    xr[4 * j + 0] = v.x;
    xr[4 * j + 1] = v.y;
    xr[4 * j + 2] = v.z;
    xr[4 * j + 3] = v.w;
  }
  float xx = 0.f;
#pragma unroll
  for (int j = 0; j < DD; ++j) xx += xr[j] * xr[j];

  float pv[KK];
  float best = 3.4e38f;
  int bi = 0;
#pragma unroll
  for (int k = 0; k < KK; ++k) {
    float dot = 0.f;
#pragma unroll
    for (int j = 0; j < DD; ++j)
      dot += xr[j] * centers[k * DD + j];  // uniform addr -> s_load (K$)
    const float d2 = xx - 2.0f * dot + cnS[k];
    pv[k] = d2;
    if (d2 < best) { best = d2; bi = k; }  // strict < == first-index ties
  }
  pred_g[row] = (unsigned char)bi;
  atomicAdd(&histS[bi], 1);

  float ssum = 0.f;
#pragma unroll
  for (int k = 0; k < KK; ++k) {
    const float e = __expf(BETA_C * (best - pv[k]));
    pv[k] = e;
    ssum += e;
  }
  const float inv = 1.0f / ssum;
#pragma unroll
  for (int k = 0; k < KK; ++k) pv[k] *= inv;

#pragma unroll
  for (int m = 32; m >= 1; m >>= 1) {
    const bool hi = (lane & m) != 0;
#pragma unroll
    for (int i = 0; i < m; ++i) {
      const float send = hi ? pv[i] : pv[i + m];
      const float recv = __shfl_xor(send, m, 64);
      const float keep = hi ? pv[i + m] : pv[i];
      pv[i] = keep + recv;
    }
  }
  fillW[wid][lane] = pv[0];
  __syncthreads();
  if (tid < KK) {
    fillPart[b * KK + tid] =
        fillW[0][tid] + fillW[1][tid] + fillW[2][tid] + fillW[3][tid];
    histPart[b * KK + tid] = histS[tid];
  }
}

// planner v4: fold histPart (coalesced) -> hist, then R8-verbatim wave scans
// + worker table; also exports per-cluster worker ranges (woffK/nwK).
__global__ __launch_bounds__(256) void planner_kernel(
    const int* __restrict__ histPart, int* __restrict__ hist_g,
    int* __restrict__ cursor, unsigned char* __restrict__ wk,
    int* __restrict__ wbase, int* __restrict__ wcnt, int* __restrict__ woffK,
    int* __restrict__ nwK) {
  __shared__ int part[256];
  __shared__ int cntS[KK];
  const int t = threadIdx.x;
  const int k = t & 63, q = t >> 6;  // 4 quarters per cluster
  int s = 0;
  for (int b = q * (NB1 / 4); b < (q + 1) * (NB1 / 4); ++b)
    s += histPart[b * KK + k];  // lanes k=0..63 -> coalesced 256B per b
  part[t] = s;
  __syncthreads();
  if (t < KK) cntS[t] = part[t] + part[t + 64] + part[t + 128] + part[t + 192];
  __syncthreads();
  if (t < KK) {  // single wave, R8-verbatim scans
    const int c = cntS[t];
    hist_g[t] = c;

    int inc = c;
#pragma unroll
    for (int off = 1; off < 64; off <<= 1) {
      const int v = __shfl_up(inc, off, 64);
      if (t >= off) inc += v;
    }
    const int seg = inc - c;
    cursor[t] = seg;

    const int nw = (c + WROWS - 1) / WROWS;
    int winc = nw;
#pragma unroll
    for (int off = 1; off < 64; off <<= 1) {
      const int v = __shfl_up(winc, off, 64);
      if (t >= off) winc += v;
    }
    const int woff = winc - nw;
    const int wtot = __shfl(winc, 63, 64);
    woffK[t] = woff;
    nwK[t] = nw;

    for (int wi = 0; wi < nw; ++wi) {
      wk[woff + wi] = (unsigned char)t;
      wbase[woff + wi] = seg + wi * WROWS;
      wcnt[woff + wi] = min(WROWS, c - wi * WROWS);
    }
    for (int w = wtot + t; w < GRIDW; w += 64) wk[w] = 255;
  }
}

// scatter (R8 verbatim, validated): counting-sort x into xsort.
__global__ __launch_bounds__(256) void scatter_kernel(
    const float* __restrict__ x, const unsigned char* __restrict__ pred_g,
    int* __restrict__ cursor, float* __restrict__ xsort) {
  __shared__ int histS[KK];
  __shared__ int baseS[KK];
  __shared__ int slotS[256];

  const int tid = threadIdx.x;
  if (tid < KK) histS[tid] = 0;
  __syncthreads();

  const int row = blockIdx.x * 256 + tid;
  const int bi = pred_g[row];
  const int rank = atomicAdd(&histS[bi], 1);
  __syncthreads();
  if (tid < KK) {
    const int hh = histS[tid];
    baseS[tid] = hh ? atomicAdd(&cursor[tid], hh) : 0;
  }
  __syncthreads();
  slotS[tid] = baseS[bi] + rank;
  __syncthreads();

  const float4* xin = (const float4*)x + (size_t)blockIdx.x * 2048;
  float4* xo = (float4*)xsort;
#pragma unroll
  for (int j = 0; j < 8; ++j) {
    const int f = tid + 256 * j;
    const int rl = f >> 3;
    const int pt = f & 7;
    xo[(size_t)slotS[rl] * 8 + pt] = xin[f];  // reads perfectly coalesced
  }
}

// syrk (R8-verbatim compute); flush = plain stores into a private per-worker
// partial. Slot cover (each of 528+32 written exactly once): (i1,j0) all 256
// threads; (i0,j0)/(i1,j1) iff tj<=ti (136+136); sums by tj==0 (32).
__global__ __launch_bounds__(256) void syrk_kernel(
    const float* __restrict__ xsort, const unsigned char* __restrict__ wk,
    const int* __restrict__ wbase, const int* __restrict__ wcnt,
    float* __restrict__ m2part) {
  __shared__ float xsT[DD][68];

  const int b = blockIdx.x;
  const int k = wk[b];
  if (k == 255) return;
  const int tid = threadIdx.x;
  const int base = wbase[b];
  const int total = wcnt[b];

  const int ti = tid >> 4, tj = tid & 15;
  const int i0 = ti, i1 = ti + 16, j0 = tj, j1 = tj + 16;
  float c00 = 0.f, c10 = 0.f, c11 = 0.f, sd0 = 0.f, sd1 = 0.f;

  for (int off = 0; off < total; off += 64) {
    const int cnt = min(64, total - off);
    const int cnt4 = (cnt + 3) & ~3;
    __syncthreads();
    const float* src = xsort + (size_t)(base + off) * DD;
    for (int e = tid; e < cnt * DD; e += 256)
      xsT[e & 31][e >> 5] = src[e];  // fully coalesced
    for (int e = cnt * DD + tid; e < cnt4 * DD; e += 256)
      xsT[e & 31][e >> 5] = 0.f;
    __syncthreads();
    for (int g = 0; g < (cnt4 >> 2); ++g) {
      const float4 A0 = *(const float4*)&xsT[i0][4 * g];
      const float4 A1 = *(const float4*)&xsT[i1][4 * g];
      const float4 B0 = *(const float4*)&xsT[j0][4 * g];
      const float4 B1 = *(const float4*)&xsT[j1][4 * g];
      c00 += A0.x * B0.x + A0.y * B0.y + A0.z * B0.z + A0.w * B0.w;
      c10 += A1.x * B0.x + A1.y * B0.y + A1.z * B0.z + A1.w * B0.w;
      c11 += A1.x * B1.x + A1.y * B1.y + A1.z * B1.z + A1.w * B1.w;
      if (tj == 0) {
        sd0 += A0.x + A0.y + A0.z + A0.w;
        sd1 += A1.x + A1.y + A1.z + A1.w;
      }
    }
  }

  float* P = m2part + (size_t)b * PSTR;
  P[TRI(i1, j0)] = c10;
  if (tj <= ti) {
    P[TRI(i0, j0)] = c00;
    P[TRI(i1, j1)] = c11;
  }
  if (tj == 0) {
    P[528 + i0] = sd0;
    P[528 + i1] = sd1;
  }
}

// finalize A: one block per cluster; folds its workers' partials + fillPart,
// then R8-verbatim loss math; plain-store lossPart[k] (no atomics).
__global__ __launch_bounds__(256) void finalizeA_kernel(
    const float* __restrict__ fillPart, const int* __restrict__ hist_g,
    const int* __restrict__ woffK, const int* __restrict__ nwK,
    const float* __restrict__ m2part, const float* __restrict__ ft,
    const float* __restrict__ mt, const float* __restrict__ ct,
    float* __restrict__ lossPart) {
  __shared__ float accT[560];  // 528 tri + 32 sums
  __shared__ float meanS[DD];
  __shared__ float wred[4];
  __shared__ float wred2[4];
  const int t = threadIdx.x;
  const int k = blockIdx.x;

  const int woff = woffK[k], nw = nwK[k];
  for (int e = t; e < 560; e += 256) {
    float s = 0.f;
    for (int w = 0; w < nw; ++w) s += m2part[(size_t)(woff + w) * PSTR + e];
    accT[e] = s;
  }

  float fs = 0.f;
  for (int i = t; i < NB1; i += 256) fs += fillPart[i * KK + k];
  fs += __shfl_xor(fs, 32, 64);
  fs += __shfl_xor(fs, 16, 64);
  fs += __shfl_xor(fs, 8, 64);
  fs += __shfl_xor(fs, 4, 64);
  fs += __shfl_xor(fs, 2, 64);
  fs += __shfl_xor(fs, 1, 64);
  if ((t & 63) == 0) wred2[t >> 6] = fs;
  __syncthreads();  // accT + wred2 ready

  const float inv = 1.0f / fmaxf((float)hist_g[k], 1.0f);
  if (t < DD) meanS[t] = accT[528 + t] * inv;
  __syncthreads();

  float acc = 0.f;
  if (t < DD) {
    const float d = meanS[t] - mt[k * DD + t];
    acc += d * d * (1.0f / (KK * DD));
  }
  if (t == 0) {
    const float S = wred2[0] + wred2[1] + wred2[2] + wred2[3];
    const float f = S * (1.0f / (float)NR) - ft[k];
    acc += f * f * (1.0f / KK);
  }
  const float* ctk = ct + k * (DD * DD);
#pragma unroll
  for (int u = 0; u < 4; ++u) {
    const int e = t + 256 * u;
    const int i = e >> 5, j = e & 31;
    const int idx = (i >= j) ? TRI(i, j) : TRI(j, i);
    const float cov = accT[idx] * inv - meanS[i] * meanS[j];
    const float d = cov - ctk[e];
    acc += d * d * (1.0f / (KK * DD * DD));
  }

  acc += __shfl_xor(acc, 32, 64);
  acc += __shfl_xor(acc, 16, 64);
  acc += __shfl_xor(acc, 8, 64);
  acc += __shfl_xor(acc, 4, 64);
  acc += __shfl_xor(acc, 2, 64);
  acc += __shfl_xor(acc, 1, 64);
  if ((t & 63) == 0) wred[t >> 6] = acc;
  __syncthreads();
  if (t == 0) lossPart[k] = wred[0] + wred[1] + wred[2] + wred[3];
}

// finalize B: sum the 64 per-cluster loss partials -> scalar out.
__global__ void finalizeB_kernel(const float* __restrict__ lossPart,
                                 float* __restrict__ out) {
  const int t = threadIdx.x;  // 64
  float v = lossPart[t];
  v += __shfl_xor(v, 32, 64);
  v += __shfl_xor(v, 16, 64);
  v += __shfl_xor(v, 8, 64);
  v += __shfl_xor(v, 4, 64);
  v += __shfl_xor(v, 2, 64);
  v += __shfl_xor(v, 1, 64);
  if (t == 0) out[0] = v;
}

extern "C" void kernel_launch(void* const* d_in, const int* in_sizes, int n_in,
                              void* d_out, int out_size, void* d_ws,
                              size_t ws_size, hipStream_t stream) {
  (void)in_sizes; (void)n_in; (void)out_size; (void)ws_size;
  const float* x = (const float*)d_in[0];
  const float* centers = (const float*)d_in[1];
  const float* ft = (const float*)d_in[2];
  const float* mt = (const float*)d_in[3];
  const float* ct = (const float*)d_in[4];
  float* out = (float*)d_out;

  float* ws = (float*)d_ws;
  int* hist_g = (int*)ws;                                // 64
  int* woffK = (int*)(ws + 64);                          // 64
  int* nwK = (int*)(ws + 128);                           // 64
  int* cursor = (int*)(ws + 192);                        // 64
  unsigned char* wk = (unsigned char*)(ws + 256);        // GRIDW bytes
  int* wbase = (int*)(ws + 416);                         // GRIDW
  int* wcnt = (int*)(ws + 1056);                         // GRIDW
  float* lossPart = ws + 1696;                           // 64
  float* fillPart = ws + 2048;                           // NB1*KK
  int* histPart = (int*)(ws + 34816);                    // NB1*KK
  unsigned char* pred8 = (unsigned char*)(ws + 67584);   // N bytes
  float* m2part = ws + 100352;                           // GRIDW*PSTR
  float* xsort = ws + 468992;                            // N*D floats

  // no memset: all read slots are unconditionally written upstream.
  phase1_kernel<<<NB1, 256, 0, stream>>>(x, centers, fillPart, histPart,
                                         pred8);
  planner_kernel<<<1, 256, 0, stream>>>(histPart, hist_g, cursor, wk, wbase,
                                        wcnt, woffK, nwK);
  scatter_kernel<<<NB1, 256, 0, stream>>>(x, pred8, cursor, xsort);
  syrk_kernel<<<GRIDW, 256, 0, stream>>>(xsort, wk, wbase, wcnt, m2part);
  finalizeA_kernel<<<KK, 256, 0, stream>>>(fillPart, hist_g, woffK, nwK,
                                           m2part, ft, mt, ct, lossPart);
  finalizeB_kernel<<<1, 64, 0, stream>>>(lossPart, out);
}